// Round 14
// baseline (365.234 us; speedup 1.0000x reference)
//
#include <hip/hip_runtime.h>
#include <hip/hip_bf16.h>
#include <stdint.h>

typedef __bf16 bf16;
typedef __bf16 bf16x8 __attribute__((ext_vector_type(8)));
typedef __bf16 bf16x4 __attribute__((ext_vector_type(4)));
typedef float f32x4 __attribute__((ext_vector_type(4)));

#define B_ 8
#define N_ 4096
#define C_ 768
#define H_ 12
#define M_ 64
#define D_ 64
#define NT_ 32768
#define C3_ 2304

typedef __attribute__((address_space(3))) void lds_void_t;
typedef const __attribute__((address_space(1))) void gvoid_t;

__device__ __forceinline__ void gl_lds16(const void* gsrc, void* ldst) {
  __builtin_amdgcn_global_load_lds((gvoid_t*)(uintptr_t)gsrc,
                                   (lds_void_t*)(uintptr_t)ldst, 16, 0, 0);
}

__device__ __forceinline__ f32x4 mfma16(bf16x8 a, bf16x8 b, f32x4 c) {
  return __builtin_amdgcn_mfma_f32_16x16x32_bf16(a, b, c, 0, 0, 0);
}

#define VMW8 asm volatile("s_waitcnt vmcnt(8)" ::: "memory")
#define VMW4 asm volatile("s_waitcnt vmcnt(4)" ::: "memory")
#define VMW0 asm volatile("s_waitcnt vmcnt(0)" ::: "memory")
#define RAWBAR() { __builtin_amdgcn_sched_barrier(0); __builtin_amdgcn_s_barrier(); __builtin_amdgcn_sched_barrier(0); }

// ---------------- fused fp32 -> bf16 convert (x, w_qkv, w_proj in one launch) ----------------
#define NX4   6291456
#define NW14  442368
#define NW24  147456
__global__ void k_cvt3(const float* __restrict__ x, bf16* __restrict__ xo,
                       const float* __restrict__ w1, bf16* __restrict__ w1o,
                       const float* __restrict__ w2, bf16* __restrict__ w2o) {
  const int stride = gridDim.x * blockDim.x;
  for (int i = blockIdx.x * blockDim.x + threadIdx.x; i < NX4 + NW14 + NW24; i += stride) {
    const float* src; bf16* dst; int idx;
    if (i < NX4)              { src = x;  dst = xo;  idx = i; }
    else if (i < NX4 + NW14)  { src = w1; dst = w1o; idx = i - NX4; }
    else                      { src = w2; dst = w2o; idx = i - NX4 - NW14; }
    f32x4 v = *(const f32x4*)(src + (size_t)idx * 4);
    bf16x4 o;
    o[0] = (bf16)v[0]; o[1] = (bf16)v[1]; o[2] = (bf16)v[2]; o[3] = (bf16)v[3];
    *(bf16x4*)(dst + (size_t)idx * 4) = o;
  }
}

// ---------------- QKV GEMM: 256x256 tile, BK=32, 4-ring LDS, read-ahead pipeline (frozen; ~149us) ----------------
__global__ __launch_bounds__(512, 2) void k_qkv(
    const bf16* __restrict__ xbf, const bf16* __restrict__ wbf,
    bf16* __restrict__ Qb, bf16* __restrict__ Kb, bf16* __restrict__ Vb,
    float* __restrict__ Qlf, float* __restrict__ Klf)
{
  __shared__ bf16 As[4][8192];
  __shared__ bf16 Bs[4][8192];
  const int t = threadIdx.x;
  const int wave = t >> 6, lane = t & 63;
  const int l15 = lane & 15, l16 = lane >> 4;

  const int bid = blockIdx.x;
  const int swz = (bid & 7) * 144 + (bid >> 3);
  const int bt = swz / 9, ct = swz % 9;
  const int row0 = bt * 256, ct0 = ct * 256;
  const int wr = wave >> 2, wc = wave & 3;

  const int srow = t >> 2;
  const int scol = (((t & 3) ^ ((t >> 3) & 3)) << 3);
  const bf16* gaBase = xbf + (size_t)(row0 + srow) * C_ + scol;
  const bf16* gbBase = wbf + (size_t)(ct0 + srow) * C_ + scol;

  const int aoff = (wr * 128 + l15) * 32 + ((l16 ^ ((l15 >> 1) & 3)) << 3);
  const int boff = (wc * 64 + l15) * 32 + ((l16 ^ ((l15 >> 1) & 3)) << 3);

  f32x4 acc[8][4] = {};
  bf16x8 afr0[4], afr1[4], bfr[2][4];

#define QSTAGE(kt3) {                                                            \
    const int sb_ = (kt3) & 3;                                                   \
    gl_lds16(gaBase + (kt3) * 32, &As[sb_][t * 8]);                              \
    gl_lds16(gbBase + (kt3) * 32, &Bs[sb_][t * 8]);                              \
    gl_lds16(gaBase + (size_t)128 * C_ + (kt3) * 32, &As[sb_][(t + 512) * 8]);   \
    gl_lds16(gbBase + (size_t)128 * C_ + (kt3) * 32, &Bs[sb_][(t + 512) * 8]); }

#define QKSTEP(kt, DO_STAGE, DO_NXT, VMW_, DO_BAR) {                             \
    if (DO_STAGE) QSTAGE((kt) + 3);                                             \
    { const bf16* asC = As[(kt) & 3];                                            \
      _Pragma("unroll")                                                          \
      for (int i = 0; i < 4; ++i)                                                \
        afr1[i] = *(const bf16x8*)&asC[aoff + (4 + i) * 512]; }                  \
    __builtin_amdgcn_s_setprio(1);                                               \
    _Pragma("unroll")                                                            \
    for (int i = 0; i < 4; ++i)                                                  \
      _Pragma("unroll")                                                          \
      for (int j = 0; j < 4; ++j)                                                \
        acc[i][j] = mfma16(afr0[i], bfr[(kt) & 1][j], acc[i][j]);                \
    __builtin_amdgcn_s_setprio(0);                                               \
    if (DO_NXT) {                                                                \
      const bf16* asN = As[((kt) + 1) & 3];                                      \
      const bf16* bsN = Bs[((kt) + 1) & 3];                                      \
      _Pragma("unroll")                                                          \
      for (int i = 0; i < 4; ++i)                                                \
        afr0[i] = *(const bf16x8*)&asN[aoff + i * 512];                          \
      _Pragma("unroll")                                                          \
      for (int j = 0; j < 4; ++j)                                                \
        bfr[((kt) + 1) & 1][j] = *(const bf16x8*)&bsN[boff + j * 512]; }         \
    __builtin_amdgcn_s_setprio(1);                                               \
    _Pragma("unroll")                                                            \
    for (int i = 0; i < 4; ++i)                                                  \
      _Pragma("unroll")                                                          \
      for (int j = 0; j < 4; ++j)                                                \
        acc[4 + i][j] = mfma16(afr1[i], bfr[(kt) & 1][j], acc[4 + i][j]);        \
    __builtin_amdgcn_s_setprio(0);                                               \
    VMW_;                                                                        \
    if (DO_BAR) RAWBAR(); }

  QSTAGE(0); QSTAGE(1); QSTAGE(2);
  VMW4;
  RAWBAR();
#pragma unroll
  for (int i = 0; i < 4; ++i) afr0[i] = *(const bf16x8*)&As[0][aoff + i * 512];
#pragma unroll
  for (int j = 0; j < 4; ++j) bfr[0][j] = *(const bf16x8*)&Bs[0][boff + j * 512];

  QKSTEP(0, 1, 1, VMW4, 1)  QKSTEP(1, 1, 1, VMW4, 1)  QKSTEP(2, 1, 1, VMW4, 1)
  QKSTEP(3, 1, 1, VMW4, 1)  QKSTEP(4, 1, 1, VMW4, 1)  QKSTEP(5, 1, 1, VMW4, 1)
  QKSTEP(6, 1, 1, VMW4, 1)  QKSTEP(7, 1, 1, VMW4, 1)  QKSTEP(8, 1, 1, VMW4, 1)
  QKSTEP(9, 1, 1, VMW4, 1)  QKSTEP(10, 1, 1, VMW4, 1) QKSTEP(11, 1, 1, VMW4, 1)
  QKSTEP(12, 1, 1, VMW4, 1) QKSTEP(13, 1, 1, VMW4, 1) QKSTEP(14, 1, 1, VMW4, 1)
  QKSTEP(15, 1, 1, VMW4, 1) QKSTEP(16, 1, 1, VMW4, 1) QKSTEP(17, 1, 1, VMW4, 1)
  QKSTEP(18, 1, 1, VMW4, 1) QKSTEP(19, 1, 1, VMW4, 1) QKSTEP(20, 1, 1, VMW4, 1)
  QKSTEP(21, 0, 1, VMW0, 1)
  QKSTEP(22, 0, 1, (void)0, 1)
  QKSTEP(23, 0, 0, (void)0, 0)

#undef QKSTEP
#undef QSTAGE

  const int colblock = ct0 + wc * 64;
  const int which = colblock / C_;
  const int h = (colblock % C_) / D_;
  const int b = row0 >> 12;
  const int n_base = (row0 & (N_ - 1)) + wr * 128;
  bf16* dst = (which == 0) ? Qb : (which == 1) ? Kb : Vb;
  const float scale = (which == 0) ? 0.125f : 1.0f;
  const size_t base = ((size_t)(b * H_ + h) * N_ + n_base) * D_;
#pragma unroll
  for (int i = 0; i < 8; ++i)
#pragma unroll
    for (int q = 0; q < 4; ++q) {
      const int rloc = i * 16 + l16 * 4 + q;
#pragma unroll
      for (int j = 0; j < 4; ++j) {
        const int d = j * 16 + l15;
        dst[base + (size_t)rloc * D_ + d] = (bf16)(acc[i][j][q] * scale);
      }
    }
  if (which < 2) {
    float* lmout = (which == 0) ? Qlf : Klf;
#pragma unroll
    for (int g = 0; g < 2; ++g) {
      const int m = (n_base >> 6) + g;
#pragma unroll
      for (int j = 0; j < 4; ++j) {
        float s = 0.f;
#pragma unroll
        for (int i = 4 * g; i < 4 * g + 4; ++i)
#pragma unroll
          for (int q = 0; q < 4; ++q) s += acc[i][j][q];
        s *= scale;
        s += __shfl_xor(s, 16);
        s += __shfl_xor(s, 32);
        if (l16 == 0)
          lmout[((size_t)(b * H_ + h) * M_ + m) * D_ + j * 16 + lane] = s * (1.0f / 64.0f);
      }
    }
  }
}

// ---------------- kernel2 softmax + Newton-Schulz inverse (fp32) + bf16 landmark copies ----------------
__global__ __launch_bounds__(512, 1) void k_inv(
    const float* __restrict__ Qlf, const float* __restrict__ Klf,
    float* __restrict__ pinv, bf16* __restrict__ Qlb, bf16* __restrict__ Klb)
{
  __shared__ float K2[4096];
  __shared__ float Vm[4096];
  __shared__ float KV[4096];
  __shared__ float T1[4096];
  __shared__ float U1[4096];
  __shared__ float tmp64[64];
  __shared__ float sscale;
  const int t = threadIdx.x;
  const int bh = blockIdx.x;
  const size_t off = (size_t)bh * 4096;
  for (int idx = t; idx < 4096; idx += 512) {
    const float q = Qlf[off + idx];
    T1[idx] = q;
    Qlb[off + idx] = (bf16)q;
  }
  for (int idx = t; idx < 4096; idx += 512) {
    const int r = idx >> 6, c = idx & 63;
    const float k = Klf[off + idx];
    U1[c * 64 + r] = k;
    Klb[off + idx] = (bf16)k;
  }
  __syncthreads();
  const int j0 = (t & 15) * 4;
  const int i0 = (t >> 4) * 2;

  auto MMstep = [&](const float* A, const float* Bm, float* O, float dg, float sg, float al) {
    float r2[2][4] = {};
    for (int k = 0; k < 64; ++k) {
      f32x4 bv = *(const f32x4*)&Bm[k * 64 + j0];
      const float a0 = A[(i0 + 0) * 64 + k];
      const float a1 = A[(i0 + 1) * 64 + k];
#pragma unroll
      for (int jj = 0; jj < 4; ++jj) { r2[0][jj] += a0 * bv[jj]; r2[1][jj] += a1 * bv[jj]; }
    }
#pragma unroll
    for (int ii = 0; ii < 2; ++ii)
#pragma unroll
      for (int jj = 0; jj < 4; ++jj)
        O[(i0 + ii) * 64 + j0 + jj] = al * (dg * A[(i0 + ii) * 64 + (j0 + jj)] + sg * r2[ii][jj]);
    __syncthreads();
  };

  {
    float r2[2][4] = {};
    for (int k = 0; k < 64; ++k) {
      f32x4 bv = *(const f32x4*)&U1[k * 64 + j0];
      const float a0 = T1[(i0 + 0) * 64 + k];
      const float a1 = T1[(i0 + 1) * 64 + k];
#pragma unroll
      for (int jj = 0; jj < 4; ++jj) { r2[0][jj] += a0 * bv[jj]; r2[1][jj] += a1 * bv[jj]; }
    }
#pragma unroll
    for (int ii = 0; ii < 2; ++ii)
#pragma unroll
      for (int jj = 0; jj < 4; ++jj)
        K2[(i0 + ii) * 64 + j0 + jj] = __expf(r2[ii][jj]);
  }
  __syncthreads();
  if (t < 64) {
    float s = 0.f;
    for (int k = 0; k < 64; ++k) s += K2[t * 64 + k];
    tmp64[t] = 1.0f / s;
  }
  __syncthreads();
  for (int idx = t; idx < 4096; idx += 512) K2[idx] *= tmp64[idx >> 6];
  __syncthreads();
  if (t < 64) {
    float s = 0.f;
    for (int i = 0; i < 64; ++i) s += K2[i * 64 + t];
    tmp64[t] = s;
  }
  __syncthreads();
  if (t == 0) {
    float mx = tmp64[0];
    for (int j2 = 1; j2 < 64; ++j2) mx = fmaxf(mx, tmp64[j2]);
    sscale = 1.0f / mx;
  }
  __syncthreads();
  for (int idx = t; idx < 4096; idx += 512) {
    const int r = idx >> 6, c = idx & 63;
    Vm[idx] = K2[c * 64 + r] * sscale;
  }
  __syncthreads();

  float* pV = Vm;
  float* pT = T1;
  for (int it = 0; it < 6; ++it) {
    MMstep(K2, pV, KV, 0.f, 1.f, 1.f);
    MMstep(KV, KV, pT, 7.f, -1.f, 1.f);
    MMstep(KV, pT, U1, 15.f, -1.f, 1.f);
    MMstep(pV, U1, pT, 13.f, -1.f, 0.25f);
    float* sw = pV; pV = pT; pT = sw;
  }
  for (int idx = t; idx < 4096; idx += 512) pinv[off + idx] = pV[idx];
}

// ---------------- kernel3: KVBLK=64, 2-buffer read-ahead ring, 3 blocks/CU ----------------
__global__ __launch_bounds__(256, 3) void k_k3v(
    const bf16* __restrict__ Qlb, const bf16* __restrict__ Kb, const bf16* __restrict__ Vb,
    float* __restrict__ Zpart, float* __restrict__ rspart)
{
  __shared__ bf16 Qls[64 * 64];       // swizzled
  __shared__ bf16 Ks[2][64 * 64];     // swizzled
  __shared__ bf16 Vs[2][64 * 64];     // linear
  __shared__ bf16 Ps[64 * 64];        // element-swizzled
  __shared__ float rs[64];
  const int t = threadIdx.x, wave = t >> 6, lane = t & 63;
  const int l15 = lane & 15, l16 = lane >> 4;
  const int key = l15 & 7;
  const int bh = blockIdx.x >> 3;
  const int chunk = blockIdx.x & 7;
  const size_t kvbase = (size_t)bh * N_ * D_ + (size_t)chunk * 512 * D_;
  const int srow8 = t >> 3;                              // 0..31
  const int ssw = (((t & 7) ^ ((t >> 3) & 7)) << 3);     // pre-swizzled source column

#define KVSTAGE(st, buf) {                                                      \
    const bf16* gk = Kb + kvbase + (size_t)(st) * 64 * D_;                      \
    const bf16* gv = Vb + kvbase + (size_t)(st) * 64 * D_;                      \
    gl_lds16(gk + (size_t)srow8 * 64 + ssw, &Ks[buf][t * 8]);                   \
    gl_lds16(gk + (size_t)(32 + srow8) * 64 + ssw, &Ks[buf][(t + 256) * 8]);    \
    gl_lds16(gv + t * 8, &Vs[buf][t * 8]);                                      \
    gl_lds16(gv + (t + 256) * 8, &Vs[buf][(t + 256) * 8]); }

  {
    const bf16* g = Qlb + (size_t)bh * 4096;
    gl_lds16(g + (size_t)srow8 * 64 + ssw, &Qls[t * 8]);
    gl_lds16(g + (size_t)(32 + srow8) * 64 + ssw, &Qls[(t + 256) * 8]);
  }
  if (t < 64) rs[t] = 0.f;
  KVSTAGE(0, 0);
  VMW0;
  RAWBAR();

  f32x4 z[4] = {};
  for (int st = 0; st < 8; ++st) {
    const int buf = st & 1;
    if (st < 7) KVSTAGE(st + 1, buf ^ 1);
    // S[m=64][n=64] = Ql @ Ktile^T ; wave owns 16 cols
    f32x4 sacc[4] = {};
#pragma unroll
    for (int kk = 0; kk < 2; ++kk) {
      bf16x8 af[4], bk;
#pragma unroll
      for (int i = 0; i < 4; ++i)
        af[i] = *(const bf16x8*)&Qls[(i * 16 + l15) * 64 + (((kk * 4 + l16) ^ key) << 3)];
      bk = *(const bf16x8*)&Ks[buf][(wave * 16 + l15) * 64 + (((kk * 4 + l16) ^ key) << 3)];
#pragma unroll
      for (int i = 0; i < 4; ++i)
        sacc[i] = mfma16(af[i], bk, sacc[i]);
    }
#pragma unroll
    for (int i = 0; i < 4; ++i)
#pragma unroll
      for (int q = 0; q < 4; ++q) {
        const float e0 = __expf(sacc[i][q]);
        const int m = i * 16 + l16 * 4 + q;
        const int mk = m & 7;
        // P[m][n], n = wave*16 + l15 -> phys slot (n>>3)^mk
        Ps[m * 64 + ((((wave * 2 + (l15 >> 3)) ^ mk) << 3) | (l15 & 7))] = (bf16)e0;
        float p = e0;
        p += __shfl_xor(p, 1); p += __shfl_xor(p, 2);
        p += __shfl_xor(p, 4); p += __shfl_xor(p, 8);
        if (l15 == 0) atomicAdd(&rs[m], p);
      }
    RAWBAR();   // Ps complete
    // z += P @ Vtile ; wave owns 16 d-cols
#pragma unroll
    for (int kk = 0; kk < 2; ++kk) {
      const int kbase = kk * 32 + 8 * l16;
      const int d = wave * 16 + l15;
      bf16x8 bv;
#pragma unroll
      for (int e = 0; e < 8; ++e) bv[e] = Vs[buf][(kbase + e) * 64 + d];  // row-broadcast, conflict-free
#pragma unroll
      for (int i = 0; i < 4; ++i) {
        bf16x8 ap = *(const bf16x8*)&Ps[(i * 16 + l15) * 64 + (((kk * 4 + l16) ^ key) << 3)];
        z[i] = mfma16(ap, bv, z[i]);
      }
    }
    if (st < 7) VMW0;   // next tile landed (issued ~16 MFMAs ago)
    RAWBAR();           // Ps/rs reuse safe; Ks[buf^1]/Vs[buf^1] ready
  }
#undef KVSTAGE

  const size_t zbase = ((size_t)bh * 8 + chunk) * 4096;
#pragma unroll
  for (int i = 0; i < 4; ++i)
#pragma unroll
    for (int q = 0; q < 4; ++q) {
      const int m = i * 16 + l16 * 4 + q;
      const int d = wave * 16 + l15;
      Zpart[zbase + m * 64 + d] = z[i][q];
    }
  if (t < 64) rspart[((size_t)bh * 8 + chunk) * 64 + t] = rs[t];
}

// ---------------- W = pinv @ (sum Zpart / sum rspart), stored transposed bf16 ----------------
__global__ __launch_bounds__(256, 1) void k_comb(
    const float* __restrict__ pinv, const float* __restrict__ Zpart,
    const float* __restrict__ rspart, bf16* __restrict__ Wtb)
{
  __shared__ float Pv[4096];
  __shared__ float Zn[4096];
  __shared__ float rsum[64];
  const int t = threadIdx.x, bh = blockIdx.x;
  const size_t off = (size_t)bh * 4096;
  const float* zp = Zpart + (size_t)bh * 8 * 4096;
  const float* rp = rspart + (size_t)bh * 8 * 64;
  for (int idx = t; idx < 4096; idx += 256) Pv[idx] = pinv[off + idx];
  if (t < 64) {
    float s = 0.f;
#pragma unroll
    for (int c = 0; c < 8; ++c) s += rp[c * 64 + t];
    rsum[t] = s;
  }
  __syncthreads();
  for (int idx = t; idx < 4096; idx += 256) {
    float s = 0.f;
#pragma unroll
    for (int c = 0; c < 8; ++c) s += zp[c * 4096 + idx];
    Zn[idx] = s / rsum[idx >> 6];
  }
  __syncthreads();
  const int j0 = (t & 15) * 4, i0 = (t >> 4) * 4;
  float r[4][4] = {{0.f}};
  for (int k = 0; k < 64; ++k) {
    f32x4 bv = *(const f32x4*)&Zn[k * 64 + j0];
    float a[4];
#pragma unroll
    for (int ii = 0; ii < 4; ++ii) a[ii] = Pv[(i0 + ii) * 64 + k];
#pragma unroll
    for (int ii = 0; ii < 4; ++ii)
#pragma unroll
      for (int jj = 0; jj < 4; ++jj) r[ii][jj] += a[ii] * bv[jj];
  }
#pragma unroll
  for (int ii = 0; ii < 4; ++ii)
#pragma unroll
    for (int jj = 0; jj < 4; ++jj)
      Wtb[off + (size_t)(j0 + jj) * 64 + (i0 + ii)] = (bf16)r[ii][jj];
}

// ---------------- kernel1 softmax + @W -> SV; XOR-swizzled Qs/Kls/Wts/Ps ----------------
__global__ __launch_bounds__(256, 3) void k_sv(
    const bf16* __restrict__ Qb, const bf16* __restrict__ Klb,
    const bf16* __restrict__ Wtb, bf16* __restrict__ SVb)
{
  __shared__ bf16 Qs[128 * 64];
  __shared__ bf16 Kls[64 * 64];
  __shared__ bf16 Wts[64 * 64];
  __shared__ bf16 Ps[128 * 64];
  const int t = threadIdx.x, wave = t >> 6, lane = t & 63;
  const int l15 = lane & 15, l16 = lane >> 4;
  const int key = l15 & 7;
  const int bh = blockIdx.x >> 5;
  const int nt = blockIdx.x & 31;
  const int b = bh / H_, h = bh % H_;
  const int srow8 = t >> 3;
  const int ssw = (((t & 7) ^ ((t >> 3) & 7)) << 3);
  {
    const bf16* gq = Qb + (size_t)bh * N_ * D_ + (size_t)nt * 128 * D_;
#pragma unroll
    for (int c = 0; c < 4; ++c)
      gl_lds16(gq + (size_t)(c * 32 + srow8) * 64 + ssw, &Qs[(t + c * 256) * 8]);
    const bf16* gkl = Klb + (size_t)bh * 4096;
    gl_lds16(gkl + (size_t)srow8 * 64 + ssw, &Kls[t * 8]);
    gl_lds16(gkl + (size_t)(32 + srow8) * 64 + ssw, &Kls[(t + 256) * 8]);
    const bf16* gw = Wtb + (size_t)bh * 4096;
    gl_lds16(gw + (size_t)srow8 * 64 + ssw, &Wts[t * 8]);
    gl_lds16(gw + (size_t)(32 + srow8) * 64 + ssw, &Wts[(t + 256) * 8]);
  }
  __syncthreads();
  f32x4 sacc[2][4] = {};
#pragma unroll
  for (int kk = 0; kk < 2; ++kk) {
    bf16x8 af[2], bl[4];
#pragma unroll
    for (int r = 0; r < 2; ++r)
      af[r] = *(const bf16x8*)&Qs[(wave * 32 + r * 16 + l15) * 64 + (((kk * 4 + l16) ^ key) << 3)];
#pragma unroll
    for (int j = 0; j < 4; ++j)
      bl[j] = *(const bf16x8*)&Kls[(j * 16 + l15) * 64 + (((kk * 4 + l16) ^ key) << 3)];
#pragma unroll
    for (int r = 0; r < 2; ++r)
#pragma unroll
      for (int j = 0; j < 4; ++j)
        sacc[r][j] = mfma16(af[r], bl[j], sacc[r][j]);
  }
#pragma unroll
  for (int r = 0; r < 2; ++r)
#pragma unroll
    for (int q = 0; q < 4; ++q) {
      float e[4]; float s = 0.f;
#pragma unroll
      for (int j = 0; j < 4; ++j) { e[j] = __expf(sacc[r][j][q]); s += e[j]; }
      s += __shfl_xor(s, 1); s += __shfl_xor(s, 2);
      s += __shfl_xor(s, 4); s += __shfl_xor(s, 8);
      const float is = 1.0f / s;
      const int row = wave * 32 + r * 16 + l16 * 4 + q;
      const int rk = row & 7;
#pragma unroll
      for (int j = 0; j < 4; ++j) {
        const int col = j * 16 + l15;
        Ps[row * 64 + ((((col >> 3) ^ rk) << 3) | (col & 7))] = (bf16)(e[j] * is);
      }
    }
  __syncthreads();
  f32x4 oacc[2][4] = {};
#pragma unroll
  for (int kk = 0; kk < 2; ++kk) {
    bf16x8 af[2], bw[4];
#pragma unroll
    for (int r = 0; r < 2; ++r)
      af[r] = *(const bf16x8*)&Ps[(wave * 32 + r * 16 + l15) * 64 + (((kk * 4 + l16) ^ key) << 3)];
#pragma unroll
    for (int j = 0; j < 4; ++j)
      bw[j] = *(const bf16x8*)&Wts[(j * 16 + l15) * 64 + (((kk * 4 + l16) ^ key) << 3)];
#pragma unroll
    for (int r = 0; r < 2; ++r)
#pragma unroll
      for (int j = 0; j < 4; ++j)
        oacc[r][j] = mfma16(af[r], bw[j], oacc[r][j]);
  }
  const size_t outbase = ((size_t)b * N_ + (size_t)nt * 128) * C_ + h * 64;
#pragma unroll
  for (int r = 0; r < 2; ++r)
#pragma unroll
    for (int q = 0; q < 4; ++q) {
      const int row = wave * 32 + r * 16 + l16 * 4 + q;
#pragma unroll
      for (int j = 0; j < 4; ++j)
        SVb[outbase + (size_t)row * C_ + j * 16 + l15] = (bf16)(oacc[r][j][q]);
    }
}

// ---------------- out = SV @ w_proj^T + b_proj + V residual (128^2, read-ahead pipeline) ----------------
__global__ __launch_bounds__(256, 3) void k_proj(
    const bf16* __restrict__ SVb, const bf16* __restrict__ wpb,
    const float* __restrict__ bproj, const bf16* __restrict__ Vb,
    float* __restrict__ outp)
{
  __shared__ bf16 As[4][4096];
  __shared__ bf16 Bs[4][4096];
  const int t = threadIdx.x;
  const int wave = t >> 6, lane = t & 63;
  const int l15 = lane & 15, l16 = lane >> 4;
  const int bid = blockIdx.x;
  const int swz = (bid & 7) * 192 + (bid >> 3);
  const int bt = swz / 6, ct = swz % 6;
  const int row0 = bt * 128, col0 = ct * 128;
  const int wr = wave >> 1, wc = wave & 1;

  const int srow = t >> 2;
  const int scol = (((t & 3) ^ ((t >> 3) & 3)) << 3);
  const bf16* ga = SVb + (size_t)(row0 + srow) * C_ + scol;
  const bf16* gb = wpb + (size_t)(col0 + srow) * C_ + scol;

  const int aoff = (wr * 64 + l15) * 32 + ((l16 ^ ((l15 >> 1) & 3)) << 3);
  const int boff = (wc * 64 + l15) * 32 + ((l16 ^ ((l15 >> 1) & 3)) << 3);

  f32x4 acc[4][4] = {};
  bf16x8 afr[2][4], bfr[2][4];

#define PSTAGE(kt3) {                                                          \
    const int sb_ = (kt3) & 3;                                                 \
    gl_lds16(ga + (kt3) * 32, &As[sb_][t * 8]);                                \
    gl_lds16(gb + (kt3) * 32, &Bs[sb_][t * 8]);                                \
    gl_lds16(ga + (size_t)64 * C_ + (kt3) * 32, &As[sb_][(t + 256) * 8]);      \
    gl_lds16(gb + (size_t)64 * C_ + (kt3) * 32, &Bs[sb_][(t + 256) * 8]); }

#define PKSTEP(kt, DO_STAGE, DO_NXT, VMW_, DO_BAR) {                           \
    if (DO_STAGE) PSTAGE((kt) + 3);                                            \
    if (DO_NXT) {                                                              \
      const bf16* asN = As[((kt) + 1) & 3];                                    \
      const bf16* bsN = Bs[((kt) + 1) & 3];                                    \
      _Pragma("unroll")                                                        \
      for (int i = 0; i < 4; ++i)                                              \
        afr[((kt) + 1) & 1][i] = *(const bf16x8*)&asN[aoff + i * 512];         \
      _Pragma("unroll")                                                        \
      for (int j = 0; j < 4; ++j)                                              \
        bfr[((kt) + 1) & 1][j] = *(const bf16x8*)&bsN[boff + j * 512]; }       \
    __builtin_amdgcn_s_setprio(1);                                             \
    _Pragma("unroll")                                                          \
    for (int i = 0; i < 4; ++i)                                                \
      _Pragma("unroll")                                                        \
      for (int j = 0; j < 4; ++j)                                              \
        acc[i][j] = mfma16(afr[(kt) & 1][i], bfr[(kt) & 1][j], acc[i][j]);     \
    __builtin_amdgcn_s_setprio(0);                                             \
    VMW_;                                                                      \
    if (DO_BAR) RAWBAR(); }

  PSTAGE(0); PSTAGE(1); PSTAGE(2);
  VMW4;
  RAWBAR();
#pragma unroll
  for (int i = 0; i < 4; ++i) afr[0][i] = *(const bf16x8*)&As[0][aoff + i * 512];
#pragma unroll
  for (int j = 0; j < 4; ++j) bfr[0][j] = *(const bf16x8*)&Bs[0][boff + j * 512];

  PKSTEP(0, 1, 1, VMW4, 1)  PKSTEP(1, 1, 1, VMW4, 1)  PKSTEP(2, 1, 1, VMW4, 1)
  PKSTEP(3, 1, 1, VMW4, 1)  PKSTEP(4, 1, 1, VMW4, 1)  PKSTEP(5, 1, 1, VMW4, 1)
  PKSTEP(6, 1, 1, VMW4, 1)  PKSTEP(7, 1, 1, VMW4, 1)  PKSTEP(8, 1, 1, VMW4, 1)
  PKSTEP(9, 1, 1, VMW4, 1)  PKSTEP(10, 1, 1, VMW4, 1) PKSTEP(11, 1, 1, VMW4, 1)
  PKSTEP(12, 1, 1, VMW4, 1) PKSTEP(13, 1, 1, VMW4, 1) PKSTEP(14, 1, 1, VMW4, 1)
  PKSTEP(15, 1, 1, VMW4, 1) PKSTEP(16, 1, 1, VMW4, 1) PKSTEP(17, 1, 1, VMW4, 1)
  PKSTEP(18, 1, 1, VMW4, 1) PKSTEP(19, 1, 1, VMW4, 1) PKSTEP(20, 1, 1, VMW4, 1)
  PKSTEP(21, 0, 1, VMW0, 1)
  PKSTEP(22, 0, 1, (void)0, 1)
  PKSTEP(23, 0, 0, (void)0, 0)

#undef PKSTEP
#undef PSTAGE

#pragma unroll
  for (int i = 0; i < 4; ++i)
#pragma unroll
    for (int q = 0; q < 4; ++q) {
      const int row = row0 + wr * 64 + i * 16 + l16 * 4 + q;
      const int b = row >> 12, n = row & (N_ - 1);
#pragma unroll
      for (int j = 0; j < 4; ++j) {
        const int col = col0 + wc * 64 + j * 16 + l15;
        const int h = col >> 6, d = col & 63;
        const float v = acc[i][j][q] + bproj[col] +
                        (float)Vb[((size_t)(b * H_ + h) * N_ + n) * D_ + d];
        outp[(size_t)row * C_ + col] = v;
      }
    }
}

extern "C" void kernel_launch(void* const* d_in, const int* in_sizes, int n_in,
                              void* d_out, int out_size, void* d_ws, size_t ws_size,
                              hipStream_t stream) {
  const float* x = (const float*)d_in[0];
  const float* wqkv = (const float*)d_in[1];
  const float* wproj = (const float*)d_in[2];
  const float* bproj = (const float*)d_in[3];
  float* outp = (float*)d_out;
  char* ws = (char*)d_ws;

  size_t off = 0;
  auto take = [&](size_t bytes) { char* p = ws + off; off += bytes; return p; };
  bf16* xbf     = (bf16*)take(50331648);   // [NT,C]  (reused as SVb later)
  bf16* wqkvbf  = (bf16*)take(3538944);    // [C3,C]
  bf16* wprojbf = (bf16*)take(1179648);    // [C,C]
  bf16* Qb      = (bf16*)take(50331648);   // [B,H,N,D] scaled
  bf16* Kb      = (bf16*)take(50331648);
  bf16* Vb      = (bf16*)take(50331648);
  float* Qlf    = (float*)take(1572864);   // [B,H,M,D] fp32
  float* Klf    = (float*)take(1572864);
  bf16* Qlb     = (bf16*)take(786432);
  bf16* Klb     = (bf16*)take(786432);
  float* pinvp  = (float*)take(1572864);   // [B,H,M,M]
  float* Zpart  = (float*)take(12582912);  // [B*H][8][64][64]
  float* rspart = (float*)take(196608);    // [B*H][8][64]
  bf16* Wtb     = (bf16*)take(786432);     // [B,H,D,M]
  bf16* SVb     = xbf;  // alias: x no longer needed after k_qkv

  k_cvt3<<<2048, 256, 0, stream>>>(x, xbf, wqkv, wqkvbf, wproj, wprojbf);
  k_qkv<<<1152, 512, 0, stream>>>(xbf, wqkvbf, Qb, Kb, Vb, Qlf, Klf);
  k_inv<<<96, 512, 0, stream>>>(Qlf, Klf, pinvp, Qlb, Klb);
  k_k3v<<<768, 256, 0, stream>>>(Qlb, Kb, Vb, Zpart, rspart);
  k_comb<<<96, 256, 0, stream>>>(pinvp, Zpart, rspart, Wtb);
  k_sv<<<96 * 32, 256, 0, stream>>>(Qb, Klb, Wtb, SVb);
  k_proj<<<1536, 256, 0, stream>>>(SVb, wprojbf, bproj, Vb, outp);
}

// Round 15
// 362.348 us; speedup vs baseline: 1.0080x; 1.0080x over previous
//
#include <hip/hip_runtime.h>
#include <hip/hip_bf16.h>
#include <stdint.h>

typedef __bf16 bf16;
typedef __bf16 bf16x8 __attribute__((ext_vector_type(8)));
typedef __bf16 bf16x4 __attribute__((ext_vector_type(4)));
typedef float f32x4 __attribute__((ext_vector_type(4)));

#define B_ 8
#define N_ 4096
#define C_ 768
#define H_ 12
#define M_ 64
#define D_ 64
#define NT_ 32768
#define C3_ 2304

typedef __attribute__((address_space(3))) void lds_void_t;
typedef const __attribute__((address_space(1))) void gvoid_t;

__device__ __forceinline__ void gl_lds16(const void* gsrc, void* ldst) {
  __builtin_amdgcn_global_load_lds((gvoid_t*)(uintptr_t)gsrc,
                                   (lds_void_t*)(uintptr_t)ldst, 16, 0, 0);
}

__device__ __forceinline__ f32x4 mfma16(bf16x8 a, bf16x8 b, f32x4 c) {
  return __builtin_amdgcn_mfma_f32_16x16x32_bf16(a, b, c, 0, 0, 0);
}

#define VMW8 asm volatile("s_waitcnt vmcnt(8)" ::: "memory")
#define VMW4 asm volatile("s_waitcnt vmcnt(4)" ::: "memory")
#define VMW0 asm volatile("s_waitcnt vmcnt(0)" ::: "memory")
#define RAWBAR() { __builtin_amdgcn_sched_barrier(0); __builtin_amdgcn_s_barrier(); __builtin_amdgcn_sched_barrier(0); }

// ---------------- fused fp32 -> bf16 convert (x, w_qkv, w_proj in one launch) ----------------
#define NX4   6291456
#define NW14  442368
#define NW24  147456
__global__ void k_cvt3(const float* __restrict__ x, bf16* __restrict__ xo,
                       const float* __restrict__ w1, bf16* __restrict__ w1o,
                       const float* __restrict__ w2, bf16* __restrict__ w2o) {
  const int stride = gridDim.x * blockDim.x;
  for (int i = blockIdx.x * blockDim.x + threadIdx.x; i < NX4 + NW14 + NW24; i += stride) {
    const float* src; bf16* dst; int idx;
    if (i < NX4)              { src = x;  dst = xo;  idx = i; }
    else if (i < NX4 + NW14)  { src = w1; dst = w1o; idx = i - NX4; }
    else                      { src = w2; dst = w2o; idx = i - NX4 - NW14; }
    f32x4 v = *(const f32x4*)(src + (size_t)idx * 4);
    bf16x4 o;
    o[0] = (bf16)v[0]; o[1] = (bf16)v[1]; o[2] = (bf16)v[2]; o[3] = (bf16)v[3];
    *(bf16x4*)(dst + (size_t)idx * 4) = o;
  }
}

// ---------------- QKV GEMM: 256x256 tile, BK=32, 4-ring LDS, read-ahead pipeline (frozen; ~149us) ----------------
__global__ __launch_bounds__(512, 2) void k_qkv(
    const bf16* __restrict__ xbf, const bf16* __restrict__ wbf,
    bf16* __restrict__ Qb, bf16* __restrict__ Kb, bf16* __restrict__ Vb,
    float* __restrict__ Qlf, float* __restrict__ Klf)
{
  __shared__ bf16 As[4][8192];
  __shared__ bf16 Bs[4][8192];
  const int t = threadIdx.x;
  const int wave = t >> 6, lane = t & 63;
  const int l15 = lane & 15, l16 = lane >> 4;

  const int bid = blockIdx.x;
  const int swz = (bid & 7) * 144 + (bid >> 3);
  const int bt = swz / 9, ct = swz % 9;
  const int row0 = bt * 256, ct0 = ct * 256;
  const int wr = wave >> 2, wc = wave & 3;

  const int srow = t >> 2;
  const int scol = (((t & 3) ^ ((t >> 3) & 3)) << 3);
  const bf16* gaBase = xbf + (size_t)(row0 + srow) * C_ + scol;
  const bf16* gbBase = wbf + (size_t)(ct0 + srow) * C_ + scol;

  const int aoff = (wr * 128 + l15) * 32 + ((l16 ^ ((l15 >> 1) & 3)) << 3);
  const int boff = (wc * 64 + l15) * 32 + ((l16 ^ ((l15 >> 1) & 3)) << 3);

  f32x4 acc[8][4] = {};
  bf16x8 afr0[4], afr1[4], bfr[2][4];

#define QSTAGE(kt3) {                                                            \
    const int sb_ = (kt3) & 3;                                                   \
    gl_lds16(gaBase + (kt3) * 32, &As[sb_][t * 8]);                              \
    gl_lds16(gbBase + (kt3) * 32, &Bs[sb_][t * 8]);                              \
    gl_lds16(gaBase + (size_t)128 * C_ + (kt3) * 32, &As[sb_][(t + 512) * 8]);   \
    gl_lds16(gbBase + (size_t)128 * C_ + (kt3) * 32, &Bs[sb_][(t + 512) * 8]); }

#define QKSTEP(kt, DO_STAGE, DO_NXT, VMW_, DO_BAR) {                             \
    if (DO_STAGE) QSTAGE((kt) + 3);                                             \
    { const bf16* asC = As[(kt) & 3];                                            \
      _Pragma("unroll")                                                          \
      for (int i = 0; i < 4; ++i)                                                \
        afr1[i] = *(const bf16x8*)&asC[aoff + (4 + i) * 512]; }                  \
    __builtin_amdgcn_s_setprio(1);                                               \
    _Pragma("unroll")                                                            \
    for (int i = 0; i < 4; ++i)                                                  \
      _Pragma("unroll")                                                          \
      for (int j = 0; j < 4; ++j)                                                \
        acc[i][j] = mfma16(afr0[i], bfr[(kt) & 1][j], acc[i][j]);                \
    __builtin_amdgcn_s_setprio(0);                                               \
    if (DO_NXT) {                                                                \
      const bf16* asN = As[((kt) + 1) & 3];                                      \
      const bf16* bsN = Bs[((kt) + 1) & 3];                                      \
      _Pragma("unroll")                                                          \
      for (int i = 0; i < 4; ++i)                                                \
        afr0[i] = *(const bf16x8*)&asN[aoff + i * 512];                          \
      _Pragma("unroll")                                                          \
      for (int j = 0; j < 4; ++j)                                                \
        bfr[((kt) + 1) & 1][j] = *(const bf16x8*)&bsN[boff + j * 512]; }         \
    __builtin_amdgcn_s_setprio(1);                                               \
    _Pragma("unroll")                                                            \
    for (int i = 0; i < 4; ++i)                                                  \
      _Pragma("unroll")                                                          \
      for (int j = 0; j < 4; ++j)                                                \
        acc[4 + i][j] = mfma16(afr1[i], bfr[(kt) & 1][j], acc[4 + i][j]);        \
    __builtin_amdgcn_s_setprio(0);                                               \
    VMW_;                                                                        \
    if (DO_BAR) RAWBAR(); }

  QSTAGE(0); QSTAGE(1); QSTAGE(2);
  VMW4;
  RAWBAR();
#pragma unroll
  for (int i = 0; i < 4; ++i) afr0[i] = *(const bf16x8*)&As[0][aoff + i * 512];
#pragma unroll
  for (int j = 0; j < 4; ++j) bfr[0][j] = *(const bf16x8*)&Bs[0][boff + j * 512];

  QKSTEP(0, 1, 1, VMW4, 1)  QKSTEP(1, 1, 1, VMW4, 1)  QKSTEP(2, 1, 1, VMW4, 1)
  QKSTEP(3, 1, 1, VMW4, 1)  QKSTEP(4, 1, 1, VMW4, 1)  QKSTEP(5, 1, 1, VMW4, 1)
  QKSTEP(6, 1, 1, VMW4, 1)  QKSTEP(7, 1, 1, VMW4, 1)  QKSTEP(8, 1, 1, VMW4, 1)
  QKSTEP(9, 1, 1, VMW4, 1)  QKSTEP(10, 1, 1, VMW4, 1) QKSTEP(11, 1, 1, VMW4, 1)
  QKSTEP(12, 1, 1, VMW4, 1) QKSTEP(13, 1, 1, VMW4, 1) QKSTEP(14, 1, 1, VMW4, 1)
  QKSTEP(15, 1, 1, VMW4, 1) QKSTEP(16, 1, 1, VMW4, 1) QKSTEP(17, 1, 1, VMW4, 1)
  QKSTEP(18, 1, 1, VMW4, 1) QKSTEP(19, 1, 1, VMW4, 1) QKSTEP(20, 1, 1, VMW4, 1)
  QKSTEP(21, 0, 1, VMW0, 1)
  QKSTEP(22, 0, 1, (void)0, 1)
  QKSTEP(23, 0, 0, (void)0, 0)

#undef QKSTEP
#undef QSTAGE

  const int colblock = ct0 + wc * 64;
  const int which = colblock / C_;
  const int h = (colblock % C_) / D_;
  const int b = row0 >> 12;
  const int n_base = (row0 & (N_ - 1)) + wr * 128;
  bf16* dst = (which == 0) ? Qb : (which == 1) ? Kb : Vb;
  const float scale = (which == 0) ? 0.125f : 1.0f;
  const size_t base = ((size_t)(b * H_ + h) * N_ + n_base) * D_;
#pragma unroll
  for (int i = 0; i < 8; ++i)
#pragma unroll
    for (int q = 0; q < 4; ++q) {
      const int rloc = i * 16 + l16 * 4 + q;
#pragma unroll
      for (int j = 0; j < 4; ++j) {
        const int d = j * 16 + l15;
        dst[base + (size_t)rloc * D_ + d] = (bf16)(acc[i][j][q] * scale);
      }
    }
  if (which < 2) {
    float* lmout = (which == 0) ? Qlf : Klf;
#pragma unroll
    for (int g = 0; g < 2; ++g) {
      const int m = (n_base >> 6) + g;
#pragma unroll
      for (int j = 0; j < 4; ++j) {
        float s = 0.f;
#pragma unroll
        for (int i = 4 * g; i < 4 * g + 4; ++i)
#pragma unroll
          for (int q = 0; q < 4; ++q) s += acc[i][j][q];
        s *= scale;
        s += __shfl_xor(s, 16);
        s += __shfl_xor(s, 32);
        if (l16 == 0)
          lmout[((size_t)(b * H_ + h) * M_ + m) * D_ + j * 16 + lane] = s * (1.0f / 64.0f);
      }
    }
  }
}

// ---------------- kernel2 softmax + Newton-Schulz inverse (fp32) + bf16 landmark copies ----------------
__global__ __launch_bounds__(512, 1) void k_inv(
    const float* __restrict__ Qlf, const float* __restrict__ Klf,
    float* __restrict__ pinv, bf16* __restrict__ Qlb, bf16* __restrict__ Klb)
{
  __shared__ float K2[4096];
  __shared__ float Vm[4096];
  __shared__ float KV[4096];
  __shared__ float T1[4096];
  __shared__ float U1[4096];
  __shared__ float tmp64[64];
  __shared__ float sscale;
  const int t = threadIdx.x;
  const int bh = blockIdx.x;
  const size_t off = (size_t)bh * 4096;
  for (int idx = t; idx < 4096; idx += 512) {
    const float q = Qlf[off + idx];
    T1[idx] = q;
    Qlb[off + idx] = (bf16)q;
  }
  for (int idx = t; idx < 4096; idx += 512) {
    const int r = idx >> 6, c = idx & 63;
    const float k = Klf[off + idx];
    U1[c * 64 + r] = k;
    Klb[off + idx] = (bf16)k;
  }
  __syncthreads();
  const int j0 = (t & 15) * 4;
  const int i0 = (t >> 4) * 2;

  auto MMstep = [&](const float* A, const float* Bm, float* O, float dg, float sg, float al) {
    float r2[2][4] = {};
    for (int k = 0; k < 64; ++k) {
      f32x4 bv = *(const f32x4*)&Bm[k * 64 + j0];
      const float a0 = A[(i0 + 0) * 64 + k];
      const float a1 = A[(i0 + 1) * 64 + k];
#pragma unroll
      for (int jj = 0; jj < 4; ++jj) { r2[0][jj] += a0 * bv[jj]; r2[1][jj] += a1 * bv[jj]; }
    }
#pragma unroll
    for (int ii = 0; ii < 2; ++ii)
#pragma unroll
      for (int jj = 0; jj < 4; ++jj)
        O[(i0 + ii) * 64 + j0 + jj] = al * (dg * A[(i0 + ii) * 64 + (j0 + jj)] + sg * r2[ii][jj]);
    __syncthreads();
  };

  {
    float r2[2][4] = {};
    for (int k = 0; k < 64; ++k) {
      f32x4 bv = *(const f32x4*)&U1[k * 64 + j0];
      const float a0 = T1[(i0 + 0) * 64 + k];
      const float a1 = T1[(i0 + 1) * 64 + k];
#pragma unroll
      for (int jj = 0; jj < 4; ++jj) { r2[0][jj] += a0 * bv[jj]; r2[1][jj] += a1 * bv[jj]; }
    }
#pragma unroll
    for (int ii = 0; ii < 2; ++ii)
#pragma unroll
      for (int jj = 0; jj < 4; ++jj)
        K2[(i0 + ii) * 64 + j0 + jj] = __expf(r2[ii][jj]);
  }
  __syncthreads();
  if (t < 64) {
    float s = 0.f;
    for (int k = 0; k < 64; ++k) s += K2[t * 64 + k];
    tmp64[t] = 1.0f / s;
  }
  __syncthreads();
  for (int idx = t; idx < 4096; idx += 512) K2[idx] *= tmp64[idx >> 6];
  __syncthreads();
  if (t < 64) {
    float s = 0.f;
    for (int i = 0; i < 64; ++i) s += K2[i * 64 + t];
    tmp64[t] = s;
  }
  __syncthreads();
  if (t == 0) {
    float mx = tmp64[0];
    for (int j2 = 1; j2 < 64; ++j2) mx = fmaxf(mx, tmp64[j2]);
    sscale = 1.0f / mx;
  }
  __syncthreads();
  for (int idx = t; idx < 4096; idx += 512) {
    const int r = idx >> 6, c = idx & 63;
    Vm[idx] = K2[c * 64 + r] * sscale;
  }
  __syncthreads();

  float* pV = Vm;
  float* pT = T1;
  for (int it = 0; it < 6; ++it) {
    MMstep(K2, pV, KV, 0.f, 1.f, 1.f);
    MMstep(KV, KV, pT, 7.f, -1.f, 1.f);
    MMstep(KV, pT, U1, 15.f, -1.f, 1.f);
    MMstep(pV, U1, pT, 13.f, -1.f, 0.25f);
    float* sw = pV; pV = pT; pT = sw;
  }
  for (int idx = t; idx < 4096; idx += 512) pinv[off + idx] = pV[idx];
}

// ---------------- kernel3 softmax @ V -> per-chunk partials; XOR-swizzled Qls/Ks/Ps (Vs linear) ----------------
__global__ __launch_bounds__(256, 2) void k_k3v(
    const bf16* __restrict__ Qlb, const bf16* __restrict__ Kb, const bf16* __restrict__ Vb,
    float* __restrict__ Zpart, float* __restrict__ rspart)
{
  __shared__ bf16 Qls[64 * 64];
  __shared__ bf16 Ks[128 * 64];
  __shared__ bf16 Vs[128 * 64];
  __shared__ bf16 Ps[64 * 128];
  __shared__ float rs[64];
  const int t = threadIdx.x, wave = t >> 6, lane = t & 63;
  const int l15 = lane & 15, l16 = lane >> 4;
  const int key = l15 & 7;                 // read-side XOR key (row&7)
  const int bh = blockIdx.x >> 3;
  const int chunk = blockIdx.x & 7;
  const size_t kvbase = (size_t)bh * N_ * D_ + (size_t)chunk * 512 * D_;
  const int srow8 = t >> 3;                              // staging row within 32-row pass
  const int ssw = (((t & 7) ^ ((t >> 3) & 7)) << 3);     // pre-swizzled source column
  {
    const bf16* g = Qlb + (size_t)bh * 4096;
    gl_lds16(g + (size_t)srow8 * 64 + ssw, &Qls[t * 8]);
    gl_lds16(g + (size_t)(32 + srow8) * 64 + ssw, &Qls[(t + 256) * 8]);
  }
  if (t < 64) rs[t] = 0.f;
  f32x4 z[4] = {};
  for (int st = 0; st < 4; ++st) {
    const bf16* gk = Kb + kvbase + (size_t)st * 128 * D_;
    const bf16* gv = Vb + kvbase + (size_t)st * 128 * D_;
#pragma unroll
    for (int c = 0; c < 4; ++c) {
      gl_lds16(gk + (size_t)(c * 32 + srow8) * 64 + ssw, &Ks[(t + c * 256) * 8]);  // swizzled
      gl_lds16(gv + (t + c * 256) * 8, &Vs[(t + c * 256) * 8]);                    // linear
    }
    __syncthreads();
    f32x4 sacc[4][2] = {};
#pragma unroll
    for (int kk = 0; kk < 2; ++kk) {
      bf16x8 af[4], bk[2];
#pragma unroll
      for (int i = 0; i < 4; ++i)
        af[i] = *(const bf16x8*)&Qls[(i * 16 + l15) * 64 + (((kk * 4 + l16) ^ key) << 3)];
#pragma unroll
      for (int j2 = 0; j2 < 2; ++j2)
        bk[j2] = *(const bf16x8*)&Ks[(wave * 32 + j2 * 16 + l15) * 64 + (((kk * 4 + l16) ^ key) << 3)];
#pragma unroll
      for (int i = 0; i < 4; ++i)
#pragma unroll
        for (int j2 = 0; j2 < 2; ++j2)
          sacc[i][j2] = mfma16(af[i], bk[j2], sacc[i][j2]);
    }
#pragma unroll
    for (int i = 0; i < 4; ++i)
#pragma unroll
      for (int q = 0; q < 4; ++q) {
        const float e0 = __expf(sacc[i][0][q]);
        const float e1 = __expf(sacc[i][1][q]);
        const int m = i * 16 + l16 * 4 + q;
        const int mk = m & 7;
        // P element-swizzled: phys = m*128 + (((n>>3)^mk)<<3 | (n&7)); n0=wave*32+l15, n1=n0+16
        Ps[m * 128 + ((((wave * 4 + (l15 >> 3)) ^ mk) << 3) | (l15 & 7))] = (bf16)e0;
        Ps[m * 128 + ((((wave * 4 + 2 + (l15 >> 3)) ^ mk) << 3) | (l15 & 7))] = (bf16)e1;
        float p = e0 + e1;
        p += __shfl_xor(p, 1); p += __shfl_xor(p, 2);
        p += __shfl_xor(p, 4); p += __shfl_xor(p, 8);
        if (l15 == 0) atomicAdd(&rs[m], p);
      }
    __syncthreads();
#pragma unroll
    for (int kk = 0; kk < 4; ++kk) {
      const int kbase = kk * 32 + 8 * l16;
      const int d = wave * 16 + l15;
      bf16x8 bv;
#pragma unroll
      for (int e = 0; e < 8; ++e) bv[e] = Vs[(kbase + e) * 64 + d];   // linear V^T gather (broadcast-free)
#pragma unroll
      for (int i = 0; i < 4; ++i) {
        bf16x8 ap = *(const bf16x8*)&Ps[(i * 16 + l15) * 128 + (((kk * 4 + l16) ^ key) << 3)];
        z[i] = mfma16(ap, bv, z[i]);
      }
    }
    __syncthreads();
  }
  const size_t zbase = ((size_t)bh * 8 + chunk) * 4096;
#pragma unroll
  for (int i = 0; i < 4; ++i)
#pragma unroll
    for (int q = 0; q < 4; ++q) {
      const int m = i * 16 + l16 * 4 + q;
      const int d = wave * 16 + l15;
      Zpart[zbase + m * 64 + d] = z[i][q];
    }
  if (t < 64) rspart[((size_t)bh * 8 + chunk) * 64 + t] = rs[t];
}

// ---------------- W = pinv @ (sum Zpart / sum rspart), stored transposed bf16 ----------------
__global__ __launch_bounds__(256, 1) void k_comb(
    const float* __restrict__ pinv, const float* __restrict__ Zpart,
    const float* __restrict__ rspart, bf16* __restrict__ Wtb)
{
  __shared__ float Pv[4096];
  __shared__ float Zn[4096];
  __shared__ float rsum[64];
  const int t = threadIdx.x, bh = blockIdx.x;
  const size_t off = (size_t)bh * 4096;
  const float* zp = Zpart + (size_t)bh * 8 * 4096;
  const float* rp = rspart + (size_t)bh * 8 * 64;
  for (int idx = t; idx < 4096; idx += 256) Pv[idx] = pinv[off + idx];
  if (t < 64) {
    float s = 0.f;
#pragma unroll
    for (int c = 0; c < 8; ++c) s += rp[c * 64 + t];
    rsum[t] = s;
  }
  __syncthreads();
  for (int idx = t; idx < 4096; idx += 256) {
    float s = 0.f;
#pragma unroll
    for (int c = 0; c < 8; ++c) s += zp[c * 4096 + idx];
    Zn[idx] = s / rsum[idx >> 6];
  }
  __syncthreads();
  const int j0 = (t & 15) * 4, i0 = (t >> 4) * 4;
  float r[4][4] = {{0.f}};
  for (int k = 0; k < 64; ++k) {
    f32x4 bv = *(const f32x4*)&Zn[k * 64 + j0];
    float a[4];
#pragma unroll
    for (int ii = 0; ii < 4; ++ii) a[ii] = Pv[(i0 + ii) * 64 + k];
#pragma unroll
    for (int ii = 0; ii < 4; ++ii)
#pragma unroll
      for (int jj = 0; jj < 4; ++jj) r[ii][jj] += a[ii] * bv[jj];
  }
#pragma unroll
  for (int ii = 0; ii < 4; ++ii)
#pragma unroll
    for (int jj = 0; jj < 4; ++jj)
      Wtb[off + (size_t)(j0 + jj) * 64 + (i0 + ii)] = (bf16)r[ii][jj];
}

// ---------------- kernel1 softmax + @W -> SV; XOR-swizzled Qs/Kls/Wts/Ps ----------------
__global__ __launch_bounds__(256, 3) void k_sv(
    const bf16* __restrict__ Qb, const bf16* __restrict__ Klb,
    const bf16* __restrict__ Wtb, bf16* __restrict__ SVb)
{
  __shared__ bf16 Qs[128 * 64];
  __shared__ bf16 Kls[64 * 64];
  __shared__ bf16 Wts[64 * 64];
  __shared__ bf16 Ps[128 * 64];
  const int t = threadIdx.x, wave = t >> 6, lane = t & 63;
  const int l15 = lane & 15, l16 = lane >> 4;
  const int key = l15 & 7;
  const int bh = blockIdx.x >> 5;
  const int nt = blockIdx.x & 31;
  const int b = bh / H_, h = bh % H_;
  const int srow8 = t >> 3;
  const int ssw = (((t & 7) ^ ((t >> 3) & 7)) << 3);
  {
    const bf16* gq = Qb + (size_t)bh * N_ * D_ + (size_t)nt * 128 * D_;
#pragma unroll
    for (int c = 0; c < 4; ++c)
      gl_lds16(gq + (size_t)(c * 32 + srow8) * 64 + ssw, &Qs[(t + c * 256) * 8]);
    const bf16* gkl = Klb + (size_t)bh * 4096;
    gl_lds16(gkl + (size_t)srow8 * 64 + ssw, &Kls[t * 8]);
    gl_lds16(gkl + (size_t)(32 + srow8) * 64 + ssw, &Kls[(t + 256) * 8]);
    const bf16* gw = Wtb + (size_t)bh * 4096;
    gl_lds16(gw + (size_t)srow8 * 64 + ssw, &Wts[t * 8]);
    gl_lds16(gw + (size_t)(32 + srow8) * 64 + ssw, &Wts[(t + 256) * 8]);
  }
  __syncthreads();
  f32x4 sacc[2][4] = {};
#pragma unroll
  for (int kk = 0; kk < 2; ++kk) {
    bf16x8 af[2], bl[4];
#pragma unroll
    for (int r = 0; r < 2; ++r)
      af[r] = *(const bf16x8*)&Qs[(wave * 32 + r * 16 + l15) * 64 + (((kk * 4 + l16) ^ key) << 3)];
#pragma unroll
    for (int j = 0; j < 4; ++j)
      bl[j] = *(const bf16x8*)&Kls[(j * 16 + l15) * 64 + (((kk * 4 + l16) ^ key) << 3)];
#pragma unroll
    for (int r = 0; r < 2; ++r)
#pragma unroll
      for (int j = 0; j < 4; ++j)
        sacc[r][j] = mfma16(af[r], bl[j], sacc[r][j]);
  }
#pragma unroll
  for (int r = 0; r < 2; ++r)
#pragma unroll
    for (int q = 0; q < 4; ++q) {
      float e[4]; float s = 0.f;
#pragma unroll
      for (int j = 0; j < 4; ++j) { e[j] = __expf(sacc[r][j][q]); s += e[j]; }
      s += __shfl_xor(s, 1); s += __shfl_xor(s, 2);
      s += __shfl_xor(s, 4); s += __shfl_xor(s, 8);
      const float is = 1.0f / s;
      const int row = wave * 32 + r * 16 + l16 * 4 + q;
      const int rk = row & 7;
#pragma unroll
      for (int j = 0; j < 4; ++j) {
        const int col = j * 16 + l15;
        Ps[row * 64 + ((((col >> 3) ^ rk) << 3) | (col & 7))] = (bf16)(e[j] * is);
      }
    }
  __syncthreads();
  f32x4 oacc[2][4] = {};
#pragma unroll
  for (int kk = 0; kk < 2; ++kk) {
    bf16x8 af[2], bw[4];
#pragma unroll
    for (int r = 0; r < 2; ++r)
      af[r] = *(const bf16x8*)&Ps[(wave * 32 + r * 16 + l15) * 64 + (((kk * 4 + l16) ^ key) << 3)];
#pragma unroll
    for (int j = 0; j < 4; ++j)
      bw[j] = *(const bf16x8*)&Wts[(j * 16 + l15) * 64 + (((kk * 4 + l16) ^ key) << 3)];
#pragma unroll
    for (int r = 0; r < 2; ++r)
#pragma unroll
      for (int j = 0; j < 4; ++j)
        oacc[r][j] = mfma16(af[r], bw[j], oacc[r][j]);
  }
  const size_t outbase = ((size_t)b * N_ + (size_t)nt * 128) * C_ + h * 64;
#pragma unroll
  for (int r = 0; r < 2; ++r)
#pragma unroll
    for (int q = 0; q < 4; ++q) {
      const int row = wave * 32 + r * 16 + l16 * 4 + q;
#pragma unroll
      for (int j = 0; j < 4; ++j)
        SVb[outbase + (size_t)row * C_ + j * 16 + l15] = (bf16)(oacc[r][j][q]);
    }
}

// ---------------- out = SV @ w_proj^T + b_proj + V residual (128^2, read-ahead pipeline) ----------------
__global__ __launch_bounds__(256, 3) void k_proj(
    const bf16* __restrict__ SVb, const bf16* __restrict__ wpb,
    const float* __restrict__ bproj, const bf16* __restrict__ Vb,
    float* __restrict__ outp)
{
  __shared__ bf16 As[4][4096];
  __shared__ bf16 Bs[4][4096];
  const int t = threadIdx.x;
  const int wave = t >> 6, lane = t & 63;
  const int l15 = lane & 15, l16 = lane >> 4;
  const int bid = blockIdx.x;
  const int swz = (bid & 7) * 192 + (bid >> 3);
  const int bt = swz / 6, ct = swz % 6;
  const int row0 = bt * 128, col0 = ct * 128;
  const int wr = wave >> 1, wc = wave & 1;

  const int srow = t >> 2;
  const int scol = (((t & 3) ^ ((t >> 3) & 3)) << 3);
  const bf16* ga = SVb + (size_t)(row0 + srow) * C_ + scol;
  const bf16* gb = wpb + (size_t)(col0 + srow) * C_ + scol;

  const int aoff = (wr * 64 + l15) * 32 + ((l16 ^ ((l15 >> 1) & 3)) << 3);
  const int boff = (wc * 64 + l15) * 32 + ((l16 ^ ((l15 >> 1) & 3)) << 3);

  f32x4 acc[4][4] = {};
  bf16x8 afr[2][4], bfr[2][4];

#define PSTAGE(kt3) {                                                          \
    const int sb_ = (kt3) & 3;                                                 \
    gl_lds16(ga + (kt3) * 32, &As[sb_][t * 8]);                                \
    gl_lds16(gb + (kt3) * 32, &Bs[sb_][t * 8]);                                \
    gl_lds16(ga + (size_t)64 * C_ + (kt3) * 32, &As[sb_][(t + 256) * 8]);      \
    gl_lds16(gb + (size_t)64 * C_ + (kt3) * 32, &Bs[sb_][(t + 256) * 8]); }

#define PKSTEP(kt, DO_STAGE, DO_NXT, VMW_, DO_BAR) {                           \
    if (DO_STAGE) PSTAGE((kt) + 3);                                            \
    if (DO_NXT) {                                                              \
      const bf16* asN = As[((kt) + 1) & 3];                                    \
      const bf16* bsN = Bs[((kt) + 1) & 3];                                    \
      _Pragma("unroll")                                                        \
      for (int i = 0; i < 4; ++i)                                              \
        afr[((kt) + 1) & 1][i] = *(const bf16x8*)&asN[aoff + i * 512];         \
      _Pragma("unroll")                                                        \
      for (int j = 0; j < 4; ++j)                                              \
        bfr[((kt) + 1) & 1][j] = *(const bf16x8*)&bsN[boff + j * 512]; }       \
    __builtin_amdgcn_s_setprio(1);                                             \
    _Pragma("unroll")                                                          \
    for (int i = 0; i < 4; ++i)                                                \
      _Pragma("unroll")                                                        \
      for (int j = 0; j < 4; ++j)                                              \
        acc[i][j] = mfma16(afr[(kt) & 1][i], bfr[(kt) & 1][j], acc[i][j]);     \
    __builtin_amdgcn_s_setprio(0);                                             \
    VMW_;                                                                      \
    if (DO_BAR) RAWBAR(); }

  PSTAGE(0); PSTAGE(1); PSTAGE(2);
  VMW4;
  RAWBAR();
#pragma unroll
  for (int i = 0; i < 4; ++i) afr[0][i] = *(const bf16x8*)&As[0][aoff + i * 512];
#pragma unroll
  for (int j = 0; j < 4; ++j) bfr[0][j] = *(const bf16x8*)&Bs[0][boff + j * 512];

  PKSTEP(0, 1, 1, VMW4, 1)  PKSTEP(1, 1, 1, VMW4, 1)  PKSTEP(2, 1, 1, VMW4, 1)
  PKSTEP(3, 1, 1, VMW4, 1)  PKSTEP(4, 1, 1, VMW4, 1)  PKSTEP(5, 1, 1, VMW4, 1)
  PKSTEP(6, 1, 1, VMW4, 1)  PKSTEP(7, 1, 1, VMW4, 1)  PKSTEP(8, 1, 1, VMW4, 1)
  PKSTEP(9, 1, 1, VMW4, 1)  PKSTEP(10, 1, 1, VMW4, 1) PKSTEP(11, 1, 1, VMW4, 1)
  PKSTEP(12, 1, 1, VMW4, 1) PKSTEP(13, 1, 1, VMW4, 1) PKSTEP(14, 1, 1, VMW4, 1)
  PKSTEP(15, 1, 1, VMW4, 1) PKSTEP(16, 1, 1, VMW4, 1) PKSTEP(17, 1, 1, VMW4, 1)
  PKSTEP(18, 1, 1, VMW4, 1) PKSTEP(19, 1, 1, VMW4, 1) PKSTEP(20, 1, 1, VMW4, 1)
  PKSTEP(21, 0, 1, VMW0, 1)
  PKSTEP(22, 0, 1, (void)0, 1)
  PKSTEP(23, 0, 0, (void)0, 0)

#undef PKSTEP
#undef PSTAGE

#pragma unroll
  for (int i = 0; i < 4; ++i)
#pragma unroll
    for (int q = 0; q < 4; ++q) {
      const int row = row0 + wr * 64 + i * 16 + l16 * 4 + q;
      const int b = row >> 12, n = row & (N_ - 1);
#pragma unroll
      for (int j = 0; j < 4; ++j) {
        const int col = col0 + wc * 64 + j * 16 + l15;
        const int h = col >> 6, d = col & 63;
        const float v = acc[i][j][q] + bproj[col] +
                        (float)Vb[((size_t)(b * H_ + h) * N_ + n) * D_ + d];
        outp[(size_t)row * C_ + col] = v;
      }
    }
}

extern "C" void kernel_launch(void* const* d_in, const int* in_sizes, int n_in,
                              void* d_out, int out_size, void* d_ws, size_t ws_size,
                              hipStream_t stream) {
  const float* x = (const float*)d_in[0];
  const float* wqkv = (const float*)d_in[1];
  const float* wproj = (const float*)d_in[2];
  const float* bproj = (const float*)d_in[3];
  float* outp = (float*)d_out;
  char* ws = (char*)d_ws;

  size_t off = 0;
  auto take = [&](size_t bytes) { char* p = ws + off; off += bytes; return p; };
  bf16* xbf     = (bf16*)take(50331648);   // [NT,C]  (reused as SVb later)
  bf16* wqkvbf  = (bf16*)take(3538944);    // [C3,C]
  bf16* wprojbf = (bf16*)take(1179648);    // [C,C]
  bf16* Qb      = (bf16*)take(50331648);   // [B,H,N,D] scaled
  bf16* Kb      = (bf16*)take(50331648);
  bf16* Vb      = (bf16*)take(50331648);
  float* Qlf    = (float*)take(1572864);   // [B,H,M,D] fp32
  float* Klf    = (float*)take(1572864);
  bf16* Qlb     = (bf16*)take(786432);
  bf16* Klb     = (bf16*)take(786432);
  float* pinvp  = (float*)take(1572864);   // [B,H,M,M]
  float* Zpart  = (float*)take(12582912);  // [B*H][8][64][64]
  float* rspart = (float*)take(196608);    // [B*H][8][64]
  bf16* Wtb     = (bf16*)take(786432);     // [B,H,D,M]
  bf16* SVb     = xbf;  // alias: x no longer needed after k_qkv

  k_cvt3<<<2048, 256, 0, stream>>>(x, xbf, wqkv, wqkvbf, wproj, wprojbf);
  k_qkv<<<1152, 512, 0, stream>>>(xbf, wqkvbf, Qb, Kb, Vb, Qlf, Klf);
  k_inv<<<96, 512, 0, stream>>>(Qlf, Klf, pinvp, Qlb, Klb);
  k_k3v<<<768, 256, 0, stream>>>(Qlb, Kb, Vb, Zpart, rspart);
  k_comb<<<96, 256, 0, stream>>>(pinvp, Zpart, rspart, Wtb);
  k_sv<<<96 * 32, 256, 0, stream>>>(Qb, Klb, Wtb, SVb);
  k_proj<<<1536, 256, 0, stream>>>(SVb, wprojbf, bproj, Vb, outp);
}